// Round 4
// baseline (140.579 us; speedup 1.0000x reference)
//
#include <hip/hip_runtime.h>

// RoIAlign multi-level extractor (FPN), matches jax reference:
//   K=1024 rois, C=256, OUT=7, SR=2, levels strides {4,8,16,32}, B=2
//   out[k,c,ph,pw] = mean over 2x2 samples of bilinear(feat[lvl(k)][b,c])
//
// Structure: 1 block (256 thr) per roi.
//   Phase 0: 28 threads compute per-axis sampling metadata -> LDS
//   Loop over 32 channel-groups of 8:
//     stage 28x28 corner grid per channel into LDS (lane = x-corner, row loop)
//     compute 8*49 outputs from LDS, coalesced global write

#define CCH 256
#define NS  14   // OUT*SR samples per axis
#define NG  28   // 2*NS corner rows/cols (lo then hi)

__global__ __launch_bounds__(256) void roi_extract_kernel(
    const float* __restrict__ f0, const float* __restrict__ f1,
    const float* __restrict__ f2, const float* __restrict__ f3,
    const float* __restrict__ rois, float* __restrict__ out, int K)
{
  const int k = blockIdx.x;
  const int t = threadIdx.x;

  __shared__ int   s_xidx[NG];          // x pixel index (lo[0..13], hi[0..13])
  __shared__ int   s_yoff[NG];          // y pixel index * W
  __shared__ float s_fx[NS], s_vx[NS], s_fy[NS], s_vy[NS];
  __shared__ int   s_lvl, s_boff;
  __shared__ float s_grid[8][NG][NG + 1];  // 8 channels x 28x28 corner grid (+1 pad)

  if (t < NG) {
    const float r0 = rois[k*5 + 0];
    const float x1 = rois[k*5 + 1], y1 = rois[k*5 + 2];
    const float x2 = rois[k*5 + 3], y2 = rois[k*5 + 4];

    // level mapping: clip(floor(log2(sqrt(w*h)/56 + 1e-6)), 0, 3)
    // replicate f32 op-by-op (no fma contraction); log2 via double ~= correctly
    // rounded f32 log2 (matches np.log2 float32 semantics at step boundaries)
    const float scl = __fsqrt_rn(__fmul_rn(__fsub_rn(x2, x1), __fsub_rn(y2, y1)));
    const float tq  = __fadd_rn(__fdiv_rn(scl, 56.0f), 1e-6f);
    const float lg  = (float)log2((double)tq);
    int lvl = (int)floorf(lg);
    lvl = lvl < 0 ? 0 : (lvl > 3 ? 3 : lvl);

    const int   sizeL = 256 >> lvl;               // H == W at this level
    const float ssc   = 1.0f / (float)(4 << lvl); // spatial scale

    const int axis = t / NS;       // 0 = x, 1 = y
    const int s    = t - axis*NS;  // sample index 0..13

    const float c1 = axis ? y1 : x1;
    const float c2 = axis ? y2 : x2;
    const float start = __fsub_rn(__fmul_rn(c1, ssc), 0.5f);
    const float rlen  = __fmul_rn(__fsub_rn(c2, c1), ssc);
    const float bwid  = __fdiv_rn(rlen, 7.0f);

    const int bin = s >> 1, i = s & 1;
    const float off = ((float)i + 0.5f) * 0.5f;   // (i+0.5)/SR, exact
    const float g = __fadd_rn(__fadd_rn(start, __fmul_rn((float)bin, bwid)),
                              __fmul_rn(off, bwid));

    const float valid = (g >= -1.0f && g <= (float)sizeL) ? 1.0f : 0.0f;
    float cc = fminf(fmaxf(g, 0.0f), (float)(sizeL - 1));
    const int lo0 = (int)floorf(cc);
    int lo, hi; float frac;
    if (lo0 >= sizeL - 1) { lo = sizeL - 1; hi = sizeL - 1; frac = 0.0f; }
    else                  { lo = lo0; hi = lo0 + 1; frac = cc - (float)lo0; }

    if (axis == 0) { s_xidx[s] = lo; s_xidx[NS + s] = hi; s_fx[s] = frac; s_vx[s] = valid; }
    else           { s_yoff[s] = lo * sizeL; s_yoff[NS + s] = hi * sizeL;
                     s_fy[s] = frac; s_vy[s] = valid; }
    if (t == 0) {
      s_lvl  = lvl;
      s_boff = (int)r0 * CCH * sizeL * sizeL;     // batch offset (elements)
    }
  }
  __syncthreads();

  const int lvl = s_lvl;
  const float* fp = (lvl == 0) ? f0 : (lvl == 1) ? f1 : (lvl == 2) ? f2 : f3;
  const int sz = 256 >> lvl;
  const int HW = sz * sz;
  const float* bp = fp + s_boff;

  const int csub = t >> 5;        // 0..7: channel within group
  const int lane = t & 31;        // 0..31: x-corner lane (28 active)
  const int xo   = (lane < NG) ? s_xidx[lane] : 0;

  for (int cg = 0; cg < CCH / 8; ++cg) {
    const int c0 = cg * 8;
    const float* cp = bp + (size_t)(c0 + csub) * HW;

    if (lane < NG) {
      #pragma unroll
      for (int r = 0; r < NG; ++r) {
        s_grid[csub][r][lane] = cp[s_yoff[r] + xo];
      }
    }
    __syncthreads();

    for (int o = t; o < 8 * 49; o += 256) {
      const int cs  = o / 49;
      const int bin = o - cs * 49;
      const int ph  = bin / 7, pw = bin - ph * 7;
      float acc = 0.0f;
      #pragma unroll
      for (int i = 0; i < 2; ++i) {
        const int sy = 2 * ph + i;
        const float fy = s_fy[sy], vy = s_vy[sy];
        #pragma unroll
        for (int j = 0; j < 2; ++j) {
          const int sx = 2 * pw + j;
          const float fx = s_fx[sx], vx = s_vx[sx];
          const float g00 = s_grid[cs][sy][sx];
          const float g01 = s_grid[cs][sy][NS + sx];
          const float g10 = s_grid[cs][NS + sy][sx];
          const float g11 = s_grid[cs][NS + sy][NS + sx];
          const float sval = (1.0f - fy) * ((1.0f - fx) * g00 + fx * g01)
                           + fy * ((1.0f - fx) * g10 + fx * g11);
          acc += sval * (vy * vx);
        }
      }
      out[((size_t)k * CCH + c0 + cs) * 49 + bin] = acc * 0.25f;
    }
    __syncthreads();
  }
}

extern "C" void kernel_launch(void* const* d_in, const int* in_sizes, int n_in,
                              void* d_out, int out_size, void* d_ws, size_t ws_size,
                              hipStream_t stream) {
  const float* f0   = (const float*)d_in[0];
  const float* f1   = (const float*)d_in[1];
  const float* f2   = (const float*)d_in[2];
  const float* f3   = (const float*)d_in[3];
  const float* rois = (const float*)d_in[4];
  float* out = (float*)d_out;
  const int K = in_sizes[4] / 5;

  hipLaunchKernelGGL(roi_extract_kernel, dim3(K), dim3(256), 0, stream,
                     f0, f1, f2, f3, rois, out, K);
}